// Round 6
// baseline (314.740 us; speedup 1.0000x reference)
//
#include <hip/hip_runtime.h>
#include <stdint.h>

#define NHEADS 16
#define EDIM   1024
#define SEQ    2048
#define BATCH  4

typedef float  floatx4 __attribute__((ext_vector_type(4)));
typedef __bf16 bf16x8  __attribute__((ext_vector_type(8)));
typedef unsigned short u16;

__device__ __forceinline__ u16 f2bf(float f) {
  union { float f; unsigned int u; } v; v.f = f;
  return (u16)((v.u + 0x7fffu + ((v.u >> 16) & 1u)) >> 16);
}

// pack two floats -> (bf16(hi)<<16)|bf16(lo), round-half-up, 3 VALU ops
__device__ __forceinline__ unsigned int pkbf(float lo, float hi) {
  union { float f; unsigned int u; } a, c;
  a.f = lo; c.f = hi;
  return __builtin_amdgcn_perm(c.u + 0x8000u, a.u + 0x8000u, 0x07060302u);
}

__device__ __forceinline__ void gl2lds16(const u16* g, u16* l) {
  __builtin_amdgcn_global_load_lds(
      (const __attribute__((address_space(1))) unsigned int*)g,
      (__attribute__((address_space(3))) unsigned int*)l, 16, 0, 0);
}

// ---------------- fused fp32 -> bf16 conversion, 5 regions ----------------
__global__ void cvt_all(const float* __restrict__ x,  const float* __restrict__ wq,
                        const float* __restrict__ wk, const float* __restrict__ wv,
                        const float* __restrict__ wo, u16* __restrict__ xb,
                        u16* __restrict__ wqkv, u16* __restrict__ wob, float qscale) {
  const float* src; u16* dst; int n4; float sc = 1.f;
  switch (blockIdx.y) {
    case 0: src = x;  dst = xb;             n4 = 2097152; break;
    case 1: src = wq; dst = wqkv;           n4 = 262144; sc = qscale; break;
    case 2: src = wk; dst = wqkv + 1048576; n4 = 262144; break;
    case 3: src = wv; dst = wqkv + 2097152; n4 = 262144; break;
    default: src = wo; dst = wob;           n4 = 262144; break;
  }
  const int stride = gridDim.x * blockDim.x;
  for (int i = blockIdx.x * blockDim.x + threadIdx.x; i < n4; i += stride) {
    float4 f = ((const float4*)src)[i];
    uint2 o;
    o.x = pkbf(f.x * sc, f.y * sc);
    o.y = pkbf(f.z * sc, f.w * sc);
    ((uint2*)dst)[i] = o;
  }
}

// ---- GEMM: A[n][K], B[m][K], branch-free K-loop per template MODE.
// MODE 0 (Q,K): D[e][s] -> packed uint2 along e into Cq (matid 0) / Ck (1).
// MODE 2 (V):   operands swapped -> D[s][e]; V^T stored with PERMUTED t-order
//               (pos = (s&~31)|(quad<<3)|((ni&1)<<2)) for attn's PV A-frags.
// MODE 1 (Wo):  fp32 float4 -> out[s][e].
template <int MODE>
__global__ __launch_bounds__(256, 2)
void gemm_tn(const u16* __restrict__ A, const u16* __restrict__ B,
             void* __restrict__ Cq, u16* __restrict__ Ck, u16* __restrict__ Cv,
             int Kdim) {
  __shared__ u16 As[128 * 64];
  __shared__ u16 Bs[128 * 64];
  const int tid  = threadIdx.x;
  const int w    = tid >> 6, lane = tid & 63;
  const int quad = lane >> 4, l15 = lane & 15;
  const int sr   = lane >> 3, sc8 = lane & 7;
  const int rowA0 = blockIdx.y * 128, rowB0 = blockIdx.x * 128;
  const int wrow  = (w >> 1) * 64,    wcol  = (w & 1) * 64;

  const floatx4 vzero = {0.f, 0.f, 0.f, 0.f};
  floatx4 acc[4][4];
#pragma unroll
  for (int mi = 0; mi < 4; ++mi)
#pragma unroll
    for (int ni = 0; ni < 4; ++ni) acc[mi][ni] = vzero;

  for (int k0 = 0; k0 < Kdim; k0 += 64) {
    __syncthreads();
#pragma unroll
    for (int i = 0; i < 4; ++i) {
      const int r = w * 32 + i * 8;   // 16B-chunk XOR swizzle by row&7 (= sr)
      gl2lds16(A + (size_t)(rowA0 + r + sr) * Kdim + k0 + ((sc8 ^ sr) * 8), As + r * 64);
      gl2lds16(B + (size_t)(rowB0 + r + sr) * Kdim + k0 + ((sc8 ^ sr) * 8), Bs + r * 64);
    }
    __syncthreads();
#pragma unroll
    for (int ks = 0; ks < 2; ++ks) {
      bf16x8 af[4], bfr[4];
#pragma unroll
      for (int mi = 0; mi < 4; ++mi)
        af[mi] = *(const bf16x8*)(As + (wrow + mi * 16 + l15) * 64 + (((ks * 4 + quad) ^ (l15 & 7)) * 8));
#pragma unroll
      for (int ni = 0; ni < 4; ++ni)
        bfr[ni] = *(const bf16x8*)(Bs + (wcol + ni * 16 + l15) * 64 + (((ks * 4 + quad) ^ (l15 & 7)) * 8));
#pragma unroll
      for (int mi = 0; mi < 4; ++mi)
#pragma unroll
        for (int ni = 0; ni < 4; ++ni) {
          if (MODE == 2)
            acc[mi][ni] = __builtin_amdgcn_mfma_f32_16x16x32_bf16(bfr[ni], af[mi], acc[mi][ni], 0, 0, 0);
          else
            acc[mi][ni] = __builtin_amdgcn_mfma_f32_16x16x32_bf16(af[mi], bfr[ni], acc[mi][ni], 0, 0, 0);
        }
    }
  }

  const int matid = (MODE == 0) ? (rowA0 >> 10) : 0;
#pragma unroll
  for (int mi = 0; mi < 4; ++mi)
#pragma unroll
    for (int ni = 0; ni < 4; ++ni) {
      if (MODE == 1) {
        const int e0 = rowA0 + wrow + mi * 16 + quad * 4;
        const int s  = rowB0 + wcol + ni * 16 + l15;
        *(floatx4*)((float*)Cq + (size_t)s * 1024 + e0) = acc[mi][ni];
      } else if (MODE == 0) {
        const int e0 = rowA0 + wrow + mi * 16 + quad * 4;   // 4 consecutive e
        const int s  = rowB0 + wcol + ni * 16 + l15;
        const int e_loc = e0 & 1023;
        u16* dst = (matid == 0) ? (u16*)Cq : Ck;
        uint2 pk;
        pk.x = pkbf(acc[mi][ni][0], acc[mi][ni][1]);
        pk.y = pkbf(acc[mi][ni][2], acc[mi][ni][3]);
        *(uint2*)(dst + (size_t)s * 1024 + e_loc) = pk;
      } else {
        // swapped orientation: rows = s (4 consecutive), col = e; permuted t-pos
        const int e_loc = rowA0 + wrow + mi * 16 + l15;     // < 1024
        const int s_full = rowB0 + wcol + ni * 16 + quad * 4;
        const int pos = (s_full & ~31) | (quad << 3) | ((ni & 1) << 2);
        const int bb = pos >> 11, pos_loc = pos & 2047;
        uint2 pk;
        pk.x = pkbf(acc[mi][ni][0], acc[mi][ni][1]);
        pk.y = pkbf(acc[mi][ni][2], acc[mi][ni][3]);
        *(uint2*)(Cv + (size_t)(bb * 1024 + e_loc) * SEQ + pos_loc) = pk;
      }
    }
}

// ---------------- flash attention (causal, paired q-tiles, shared A-frags) ---
// grid: x = bh (64), y = pair p (8). Block 512 = 8 waves; wave covers 16 q rows
// of BOTH tiles (tile0 qt=p, tile1 qt=15-p). Per kt, the K-tile/V-tile LDS
// fragments are loaded ONCE and feed both tiles' MFMAs (A-operands are
// tile-independent). V is pre-permuted in global so PV A-frags are single
// swizzled b128 reads. P stays in registers (C-layout as PV B-operand).
__global__ __launch_bounds__(512, 4)
void attn_fwd(const u16* __restrict__ Q, const u16* __restrict__ K,
              const u16* __restrict__ Vp, u16* __restrict__ Ctx) {
  __shared__ u16 Ks[2][128 * 64];   // [t][d], 16B-chunk XOR swizzle (t&7)
  __shared__ u16 Vs[2][64 * 128];   // [d][t-permuted], XOR swizzle (d&15)
  const int tid  = threadIdx.x;
  const int w    = tid >> 6, lane = tid & 63;
  const int quad = lane >> 4, l15 = lane & 15;
  const int bh = blockIdx.x, b = bh >> 4, h = bh & 15;
  const int p  = blockIdx.y;
  const int qts[2] = {p, 15 - p};
  const int kmax = qts[1];

  // Q B-fragments, persistent (Q pre-scaled by 0.125*log2e via Wq cvt)
  bf16x8 bq[2][2];
#pragma unroll
  for (int tt = 0; tt < 2; ++tt)
#pragma unroll
    for (int ks = 0; ks < 2; ++ks) {
      const int qs = qts[tt] * 128 + w * 16 + l15;
      bq[tt][ks] = *(const bf16x8*)(Q + (size_t)(b * SEQ + qs) * EDIM + h * 64 + ks * 32 + quad * 8);
    }

  const floatx4 vzero = {0.f, 0.f, 0.f, 0.f};
  floatx4 o_acc[2][4];              // [tile][d-tile], O^T C-layout (col = q)
  float l_run[2] = {0.f, 0.f};
#pragma unroll
  for (int tt = 0; tt < 2; ++tt)
#pragma unroll
    for (int di = 0; di < 4; ++di) o_acc[tt][di] = vzero;

  const int krow = lane >> 3, kch = lane & 7;    // K staging: 8 rows x 8 chunks
  const int vrow = lane >> 4, vch = lane & 15;   // V staging: 4 rows x 16 chunks

#define STAGE_KV(buf, ktn)                                                          \
  {                                                                                 \
    _Pragma("unroll")                                                               \
    for (int ii = 0; ii < 2; ++ii) {                                                \
      const int r0 = w * 16 + ii * 8;                                               \
      const int row = r0 + krow;                                                    \
      gl2lds16(K + (size_t)(b * SEQ + (ktn) * 128 + row) * EDIM + h * 64 +          \
                   ((kch ^ (row & 7)) * 8),                                         \
               &Ks[buf][r0 * 64]);                                                  \
      const int d0 = w * 8 + ii * 4;                                                \
      const int dd = d0 + vrow;                                                     \
      gl2lds16(Vp + (size_t)(bh * 64 + dd) * SEQ + (ktn) * 128 +                    \
                   ((vch ^ (dd & 15)) * 8),                                         \
               &Vs[buf][d0 * 128]);                                                 \
    }                                                                               \
  }

  STAGE_KV(0, 0);                   // prefetch first tile

  for (int kt = 0; kt <= kmax; ++kt) {
    const int cur = kt & 1;
    __syncthreads();                // buf[cur] drained; buf[cur^1] readers done
    if (kt < kmax) STAGE_KV(cur ^ 1, kt + 1);
    const u16* Ksc = &Ks[cur][0];
    const u16* Vsc = &Vs[cur][0];
    const bool dual = (kt <= qts[0]);

    // ---- QK for both tiles on shared K-frags; softmax fused per t-half ----
    float ls1 = 0.f, ls0 = 0.f;
    unsigned int pk1[4][4], pk0[4][4];   // [ks][dword]; pk0 used iff dual
#pragma unroll
    for (int hf = 0; hf < 2; ++hf) {
      floatx4 s1[4], s0[4];
#pragma unroll
      for (int mi = 0; mi < 4; ++mi) { s1[mi] = vzero; s0[mi] = vzero; }
#pragma unroll
      for (int ks = 0; ks < 2; ++ks) {
        bf16x8 ak[4];
#pragma unroll
        for (int mi = 0; mi < 4; ++mi)
          ak[mi] = *(const bf16x8*)(Ksc + ((hf * 4 + mi) * 16 + l15) * 64 + (((ks * 4 + quad) ^ (l15 & 7)) * 8));
#pragma unroll
        for (int mi = 0; mi < 4; ++mi)
          s1[mi] = __builtin_amdgcn_mfma_f32_16x16x32_bf16(ak[mi], bq[1][ks], s1[mi], 0, 0, 0);
        if (dual) {
#pragma unroll
          for (int mi = 0; mi < 4; ++mi)
            s0[mi] = __builtin_amdgcn_mfma_f32_16x16x32_bf16(ak[mi], bq[0][ks], s0[mi], 0, 0, 0);
        }
      }
      // causal masks (diagonal tiles only)
      const int q_loc = w * 16 + l15;
      if (kt == qts[1]) {
#pragma unroll
        for (int mi = 0; mi < 4; ++mi)
#pragma unroll
          for (int r = 0; r < 4; ++r) {
            const int t_loc = (hf * 4 + mi) * 16 + quad * 4 + r;
            if (t_loc > q_loc) s1[mi][r] = -1e30f;
          }
      }
      if (dual && kt == qts[0]) {
#pragma unroll
        for (int mi = 0; mi < 4; ++mi)
#pragma unroll
          for (int r = 0; r < 4; ++r) {
            const int t_loc = (hf * 4 + mi) * 16 + quad * 4 + r;
            if (t_loc > q_loc) s0[mi][r] = -1e30f;
          }
      }
      // exp2 + pack into PV B-operand dwords (C-layout t-order)
#pragma unroll
      for (int mi = 0; mi < 4; ++mi) {
        const int g = hf * 4 + mi;
        {
          float p0 = __builtin_amdgcn_exp2f(s1[mi][0]);
          float p1 = __builtin_amdgcn_exp2f(s1[mi][1]);
          float p2 = __builtin_amdgcn_exp2f(s1[mi][2]);
          float p3 = __builtin_amdgcn_exp2f(s1[mi][3]);
          ls1 += (p0 + p1) + (p2 + p3);
          pk1[g >> 1][(g & 1) * 2 + 0] = pkbf(p0, p1);
          pk1[g >> 1][(g & 1) * 2 + 1] = pkbf(p2, p3);
        }
        if (dual) {
          float p0 = __builtin_amdgcn_exp2f(s0[mi][0]);
          float p1 = __builtin_amdgcn_exp2f(s0[mi][1]);
          float p2 = __builtin_amdgcn_exp2f(s0[mi][2]);
          float p3 = __builtin_amdgcn_exp2f(s0[mi][3]);
          ls0 += (p0 + p1) + (p2 + p3);
          pk0[g >> 1][(g & 1) * 2 + 0] = pkbf(p0, p1);
          pk0[g >> 1][(g & 1) * 2 + 1] = pkbf(p2, p3);
        }
      }
    }
    ls1 += __shfl_xor(ls1, 16, 64);
    ls1 += __shfl_xor(ls1, 32, 64);
    l_run[1] += ls1;
    if (dual) {
      ls0 += __shfl_xor(ls0, 16, 64);
      ls0 += __shfl_xor(ls0, 32, 64);
      l_run[0] += ls0;
    }

    // ---- PV for both tiles on shared V-frags (permuted layout -> b128) ----
#pragma unroll
    for (int ks = 0; ks < 4; ++ks) {
      bf16x8 va[4];
#pragma unroll
      for (int di = 0; di < 4; ++di)
        va[di] = *(const bf16x8*)(Vsc + (di * 16 + l15) * 128 + (((ks * 4 + quad) ^ l15) * 8));
      union { unsigned int u[4]; bf16x8 v; } pb1;
      pb1.u[0] = pk1[ks][0]; pb1.u[1] = pk1[ks][1];
      pb1.u[2] = pk1[ks][2]; pb1.u[3] = pk1[ks][3];
#pragma unroll
      for (int di = 0; di < 4; ++di)
        o_acc[1][di] = __builtin_amdgcn_mfma_f32_16x16x32_bf16(va[di], pb1.v, o_acc[1][di], 0, 0, 0);
      if (dual) {
        union { unsigned int u[4]; bf16x8 v; } pb0;
        pb0.u[0] = pk0[ks][0]; pb0.u[1] = pk0[ks][1];
        pb0.u[2] = pk0[ks][2]; pb0.u[3] = pk0[ks][3];
#pragma unroll
        for (int di = 0; di < 4; ++di)
          o_acc[0][di] = __builtin_amdgcn_mfma_f32_16x16x32_bf16(va[di], pb0.v, o_acc[0][di], 0, 0, 0);
      }
    }
  }

  // epilogue: O = O^T / l, packed 8B stores along d
#pragma unroll
  for (int tt = 0; tt < 2; ++tt) {
    const float rl = 1.f / l_run[tt];
    const int qs = qts[tt] * 128 + w * 16 + l15;
#pragma unroll
    for (int di = 0; di < 4; ++di) {
      uint2 ov;
      ov.x = pkbf(o_acc[tt][di][0] * rl, o_acc[tt][di][1] * rl);
      ov.y = pkbf(o_acc[tt][di][2] * rl, o_acc[tt][di][3] * rl);
      *(uint2*)(Ctx + (size_t)(b * SEQ + qs) * EDIM + h * 64 + di * 16 + quad * 4) = ov;
    }
  }
#undef STAGE_KV
}

// ---------------- launch ----------------
extern "C" void kernel_launch(void* const* d_in, const int* in_sizes, int n_in,
                              void* d_out, int out_size, void* d_ws, size_t ws_size,
                              hipStream_t stream) {
  const float* x  = (const float*)d_in[0];
  const float* Wq = (const float*)d_in[1];
  const float* Wk = (const float*)d_in[2];
  const float* Wv = (const float*)d_in[3];
  const float* Wo = (const float*)d_in[4];
  float* out = (float*)d_out;
  u16* ws = (u16*)d_ws;

  const size_t ME = (size_t)BATCH * SEQ * EDIM;  // 8388608
  u16* Xb   = ws;                                // [8192][1024] bf16
  u16* Wqkv = Xb + ME;                           // [3072][1024]
  u16* Wob  = Wqkv + 3u * 1024 * 1024;           // [1024][1024]
  u16* Qb   = Wob + 1024u * 1024;                // [B,S,E] (pre-scaled)
  u16* Kb   = Qb + ME;
  u16* Vpb  = Kb + ME;                           // V^T permuted: [b*1024+hd][2048]
  u16* Ctx  = Vpb + ME;                          // ends at ~88 MB

  const float qscale = 0.125f * 1.44269504f;     // 1/sqrt(64) * log2(e)

  cvt_all<<<dim3(512, 5), 256, 0, stream>>>(x, Wq, Wk, Wv, Wo, Xb, Wqkv, Wob, qscale);
  gemm_tn<0><<<dim3(64, 16), 256, 0, stream>>>(Wqkv, Xb, (void*)Qb, Kb, nullptr, EDIM);
  gemm_tn<2><<<dim3(64, 8), 256, 0, stream>>>(Wqkv + 2u * 1048576, Xb, nullptr, nullptr, Vpb, EDIM);
  attn_fwd<<<dim3(64, 8), 512, 0, stream>>>(Qb, Kb, Vpb, Ctx);
  gemm_tn<1><<<dim3(64, 8), 256, 0, stream>>>(Wob, Ctx, (void*)out, nullptr, nullptr, EDIM);
}

// Round 7
// 226.343 us; speedup vs baseline: 1.3905x; 1.3905x over previous
//
#include <hip/hip_runtime.h>
#include <stdint.h>

#define NHEADS 16
#define EDIM   1024
#define SEQ    2048
#define BATCH  4

typedef float  floatx4 __attribute__((ext_vector_type(4)));
typedef __bf16 bf16x8  __attribute__((ext_vector_type(8)));
typedef unsigned short u16;

__device__ __forceinline__ u16 f2bf(float f) {
  union { float f; unsigned int u; } v; v.f = f;
  return (u16)((v.u + 0x7fffu + ((v.u >> 16) & 1u)) >> 16);
}

// pack two floats -> (bf16(hi)<<16)|bf16(lo), round-half-up, 3 VALU ops
__device__ __forceinline__ unsigned int pkbf(float lo, float hi) {
  union { float f; unsigned int u; } a, c;
  a.f = lo; c.f = hi;
  return __builtin_amdgcn_perm(c.u + 0x8000u, a.u + 0x8000u, 0x07060302u);
}

__device__ __forceinline__ void gl2lds16(const u16* g, u16* l) {
  __builtin_amdgcn_global_load_lds(
      (const __attribute__((address_space(1))) unsigned int*)g,
      (__attribute__((address_space(3))) unsigned int*)l, 16, 0, 0);
}

// ---------------- fused fp32 -> bf16 conversion, 5 regions ----------------
__global__ void cvt_all(const float* __restrict__ x,  const float* __restrict__ wq,
                        const float* __restrict__ wk, const float* __restrict__ wv,
                        const float* __restrict__ wo, u16* __restrict__ xb,
                        u16* __restrict__ wqkv, u16* __restrict__ wob, float qscale) {
  const float* src; u16* dst; int n4; float sc = 1.f;
  switch (blockIdx.y) {
    case 0: src = x;  dst = xb;             n4 = 2097152; break;
    case 1: src = wq; dst = wqkv;           n4 = 262144; sc = qscale; break;
    case 2: src = wk; dst = wqkv + 1048576; n4 = 262144; break;
    case 3: src = wv; dst = wqkv + 2097152; n4 = 262144; break;
    default: src = wo; dst = wob;           n4 = 262144; break;
  }
  const int stride = gridDim.x * blockDim.x;
  for (int i = blockIdx.x * blockDim.x + threadIdx.x; i < n4; i += stride) {
    float4 f = ((const float4*)src)[i];
    uint2 o;
    o.x = pkbf(f.x * sc, f.y * sc);
    o.y = pkbf(f.z * sc, f.w * sc);
    ((uint2*)dst)[i] = o;
  }
}

// ---- GEMM: A[n][K], B[m][K], branch-free K-loop per template MODE.
// MODE 0 (Q,K): D[e][s] -> packed uint2 along e into Cq (matid 0) / Ck (1).
// MODE 2 (V):   operands swapped -> D[s][e]; V^T stored with PERMUTED t-order
//               (pos = (s&~31)|(quad<<3)|((ni&1)<<2)) for attn's PV A-frags.
// MODE 1 (Wo):  fp32 float4 -> out[s][e].
template <int MODE>
__global__ __launch_bounds__(256, 2)
void gemm_tn(const u16* __restrict__ A, const u16* __restrict__ B,
             void* __restrict__ Cq, u16* __restrict__ Ck, u16* __restrict__ Cv,
             int Kdim) {
  __shared__ u16 As[128 * 64];
  __shared__ u16 Bs[128 * 64];
  const int tid  = threadIdx.x;
  const int w    = tid >> 6, lane = tid & 63;
  const int quad = lane >> 4, l15 = lane & 15;
  const int sr   = lane >> 3, sc8 = lane & 7;
  const int rowA0 = blockIdx.y * 128, rowB0 = blockIdx.x * 128;
  const int wrow  = (w >> 1) * 64,    wcol  = (w & 1) * 64;

  const floatx4 vzero = {0.f, 0.f, 0.f, 0.f};
  floatx4 acc[4][4];
#pragma unroll
  for (int mi = 0; mi < 4; ++mi)
#pragma unroll
    for (int ni = 0; ni < 4; ++ni) acc[mi][ni] = vzero;

  for (int k0 = 0; k0 < Kdim; k0 += 64) {
    __syncthreads();
#pragma unroll
    for (int i = 0; i < 4; ++i) {
      const int r = w * 32 + i * 8;   // 16B-chunk XOR swizzle by row&7 (= sr)
      gl2lds16(A + (size_t)(rowA0 + r + sr) * Kdim + k0 + ((sc8 ^ sr) * 8), As + r * 64);
      gl2lds16(B + (size_t)(rowB0 + r + sr) * Kdim + k0 + ((sc8 ^ sr) * 8), Bs + r * 64);
    }
    __syncthreads();
#pragma unroll
    for (int ks = 0; ks < 2; ++ks) {
      bf16x8 af[4], bfr[4];
#pragma unroll
      for (int mi = 0; mi < 4; ++mi)
        af[mi] = *(const bf16x8*)(As + (wrow + mi * 16 + l15) * 64 + (((ks * 4 + quad) ^ (l15 & 7)) * 8));
#pragma unroll
      for (int ni = 0; ni < 4; ++ni)
        bfr[ni] = *(const bf16x8*)(Bs + (wcol + ni * 16 + l15) * 64 + (((ks * 4 + quad) ^ (l15 & 7)) * 8));
#pragma unroll
      for (int mi = 0; mi < 4; ++mi)
#pragma unroll
        for (int ni = 0; ni < 4; ++ni) {
          if (MODE == 2)
            acc[mi][ni] = __builtin_amdgcn_mfma_f32_16x16x32_bf16(bfr[ni], af[mi], acc[mi][ni], 0, 0, 0);
          else
            acc[mi][ni] = __builtin_amdgcn_mfma_f32_16x16x32_bf16(af[mi], bfr[ni], acc[mi][ni], 0, 0, 0);
        }
    }
  }

  const int matid = (MODE == 0) ? (rowA0 >> 10) : 0;
#pragma unroll
  for (int mi = 0; mi < 4; ++mi)
#pragma unroll
    for (int ni = 0; ni < 4; ++ni) {
      if (MODE == 1) {
        const int e0 = rowA0 + wrow + mi * 16 + quad * 4;
        const int s  = rowB0 + wcol + ni * 16 + l15;
        *(floatx4*)((float*)Cq + (size_t)s * 1024 + e0) = acc[mi][ni];
      } else if (MODE == 0) {
        const int e0 = rowA0 + wrow + mi * 16 + quad * 4;   // 4 consecutive e
        const int s  = rowB0 + wcol + ni * 16 + l15;
        const int e_loc = e0 & 1023;
        u16* dst = (matid == 0) ? (u16*)Cq : Ck;
        uint2 pk;
        pk.x = pkbf(acc[mi][ni][0], acc[mi][ni][1]);
        pk.y = pkbf(acc[mi][ni][2], acc[mi][ni][3]);
        *(uint2*)(dst + (size_t)s * 1024 + e_loc) = pk;
      } else {
        // swapped orientation: rows = s (4 consecutive), col = e; permuted t-pos
        const int e_loc = rowA0 + wrow + mi * 16 + l15;     // < 1024
        const int s_full = rowB0 + wcol + ni * 16 + quad * 4;
        const int pos = (s_full & ~31) | (quad << 3) | ((ni & 1) << 2);
        const int bb = pos >> 11, pos_loc = pos & 2047;
        uint2 pk;
        pk.x = pkbf(acc[mi][ni][0], acc[mi][ni][1]);
        pk.y = pkbf(acc[mi][ni][2], acc[mi][ni][3]);
        *(uint2*)(Cv + (size_t)(bb * 1024 + e_loc) * SEQ + pos_loc) = pk;
      }
    }
}

// ---------------- flash attention: waves split over (q-group, t-half) --------
// grid: x = bh (64), y -> qt = 15 - y (longest first). Block 512 = 8 waves:
// wave w = (qg = w>>1)*32 q-rows x (tg = w&1)*64 t-rows. Each wave reads only
// its t-half of K/V from LDS: 8 ak + 8 va b128 per 32 MFMAs (3x fewer LDS
// reads than full-t waves). P in registers (C-layout -> PV B-operand; V
// pre-permuted in global so va are straight swizzled b128). Cross-t partial
// O and l reduced once through LDS in the epilogue.
__global__ __launch_bounds__(512, 4)
void attn_fwd(const u16* __restrict__ Q, const u16* __restrict__ K,
              const u16* __restrict__ Vp, u16* __restrict__ Ctx) {
  __shared__ u16 SMEM[4 * 8192];    // Ks[2] (2x16KB) then Vs[2] (2x16KB)
  const int tid  = threadIdx.x;
  const int w    = tid >> 6, lane = tid & 63;
  const int quad = lane >> 4, l15 = lane & 15;
  const int qg = w >> 1, tg = w & 1;
  const int bh = blockIdx.x, b = bh >> 4, h = bh & 15;
  const int qt = 15 - (int)blockIdx.y;   // longest blocks dispatched first
  const int kmax = qt;
  const int q0 = qt * 128 + qg * 32;

  // Q B-fragments (Q pre-scaled by 0.125*log2e via Wq cvt)
  bf16x8 bq[2][2];
#pragma unroll
  for (int ni = 0; ni < 2; ++ni)
#pragma unroll
    for (int ks = 0; ks < 2; ++ks) {
      const int qs = q0 + ni * 16 + l15;
      bq[ni][ks] = *(const bf16x8*)(Q + (size_t)(b * SEQ + qs) * EDIM + h * 64 + ks * 32 + quad * 8);
    }

  const floatx4 vzero = {0.f, 0.f, 0.f, 0.f};
  floatx4 o_acc[4][2];              // [d-tile][q-group], D[d][q] C-layout
  float l_acc[2] = {0.f, 0.f};      // per-lane partial row-sums
#pragma unroll
  for (int di = 0; di < 4; ++di)
#pragma unroll
    for (int ni = 0; ni < 2; ++ni) o_acc[di][ni] = vzero;

  const int krow = lane >> 3, kch = lane & 7;    // K staging: 8 rows x 8 chunks
  const int vrow = lane >> 4, vch = lane & 15;   // V staging: 4 rows x 16 chunks

#define STAGE_KV(buf, ktn)                                                          \
  {                                                                                 \
    _Pragma("unroll")                                                               \
    for (int ii = 0; ii < 2; ++ii) {                                                \
      const int r0 = w * 16 + ii * 8;                                               \
      const int row = r0 + krow;                                                    \
      gl2lds16(K + (size_t)(b * SEQ + (ktn) * 128 + row) * EDIM + h * 64 +          \
                   ((kch ^ (row & 7)) * 8),                                         \
               SMEM + (buf) * 8192 + r0 * 64);                                      \
      const int d0 = w * 8 + ii * 4;                                                \
      const int dd = d0 + vrow;                                                     \
      gl2lds16(Vp + (size_t)(bh * 64 + dd) * SEQ + (ktn) * 128 +                    \
                   ((vch ^ (dd & 15)) * 8),                                         \
               SMEM + 16384 + (buf) * 8192 + d0 * 128);                             \
    }                                                                               \
  }

  STAGE_KV(0, 0);

  for (int kt = 0; kt <= kmax; ++kt) {
    const int cur = kt & 1;
    __syncthreads();                // buf[cur] drained; buf[cur^1] readers done
    if (kt < kmax) STAGE_KV(cur ^ 1, kt + 1);
    const u16* Ksc = SMEM + cur * 8192;
    const u16* Vsc = SMEM + 16384 + cur * 8192;

    // ---- QK + fused softmax, per mi (keeps s_acc live-range at 8 regs) ----
    unsigned int pk[2][2][4];       // [ni][ks][dword] PV B-operand
#pragma unroll
    for (int mi = 0; mi < 4; ++mi) {
      floatx4 s[2] = {vzero, vzero};
#pragma unroll
      for (int ks = 0; ks < 2; ++ks) {
        bf16x8 ak = *(const bf16x8*)(Ksc + (tg * 64 + mi * 16 + l15) * 64 +
                                     (((ks * 4 + quad) ^ (l15 & 7)) * 8));
#pragma unroll
        for (int ni = 0; ni < 2; ++ni)
          s[ni] = __builtin_amdgcn_mfma_f32_16x16x32_bf16(ak, bq[ni][ks], s[ni], 0, 0, 0);
      }
      if (kt == kmax) {             // causal mask, diagonal tile only
#pragma unroll
        for (int ni = 0; ni < 2; ++ni)
#pragma unroll
          for (int r = 0; r < 4; ++r) {
            const int t_loc = tg * 64 + mi * 16 + quad * 4 + r;
            const int q_loc = qg * 32 + ni * 16 + l15;
            if (t_loc > q_loc) s[ni][r] = -1e30f;
          }
      }
#pragma unroll
      for (int ni = 0; ni < 2; ++ni) {
        float p0 = __builtin_amdgcn_exp2f(s[ni][0]);
        float p1 = __builtin_amdgcn_exp2f(s[ni][1]);
        float p2 = __builtin_amdgcn_exp2f(s[ni][2]);
        float p3 = __builtin_amdgcn_exp2f(s[ni][3]);
        l_acc[ni] += (p0 + p1) + (p2 + p3);
        pk[ni][mi >> 1][(mi & 1) * 2 + 0] = pkbf(p0, p1);
        pk[ni][mi >> 1][(mi & 1) * 2 + 1] = pkbf(p2, p3);
      }
    }

    // ---- PV on the wave's t-half (permuted layout -> swizzled b128) ----
#pragma unroll
    for (int ks = 0; ks < 2; ++ks) {
      bf16x8 va[4];
#pragma unroll
      for (int di = 0; di < 4; ++di)
        va[di] = *(const bf16x8*)(Vsc + (di * 16 + l15) * 128 +
                                  (((tg * 8 + ks * 4 + quad) ^ l15) * 8));
#pragma unroll
      for (int ni = 0; ni < 2; ++ni) {
        union { unsigned int u[4]; bf16x8 v; } pb;
        pb.u[0] = pk[ni][ks][0]; pb.u[1] = pk[ni][ks][1];
        pb.u[2] = pk[ni][ks][2]; pb.u[3] = pk[ni][ks][3];
#pragma unroll
        for (int di = 0; di < 4; ++di)
          o_acc[di][ni] = __builtin_amdgcn_mfma_f32_16x16x32_bf16(va[di], pb.v, o_acc[di][ni], 0, 0, 0);
      }
    }
  }

  // ---- epilogue: reduce tg partials through LDS, divide by l, store ----
  // in-wave l reduce (sum over quads for each q = l15 column)
  float lt[2];
#pragma unroll
  for (int ni = 0; ni < 2; ++ni) {
    float v = l_acc[ni];
    v += __shfl_xor(v, 16, 64);
    v += __shfl_xor(v, 32, 64);
    lt[ni] = v;
  }
  __syncthreads();                  // everyone done with K/V LDS
  float* red  = (float*)SMEM;       // O partials: [qg][d][q] stride 33 (8448 f)
  float* lred = red + 8448;         // l partials: [qg*32 + q] (128 f)
  if (tg == 1) {
#pragma unroll
    for (int ni = 0; ni < 2; ++ni) {
#pragma unroll
      for (int di = 0; di < 4; ++di)
#pragma unroll
        for (int r = 0; r < 4; ++r)
          red[qg * 2112 + (di * 16 + quad * 4 + r) * 33 + ni * 16 + l15] = o_acc[di][ni][r];
      if (quad == 0) lred[qg * 32 + ni * 16 + l15] = lt[ni];
    }
  }
  __syncthreads();
  if (tg == 0) {
#pragma unroll
    for (int ni = 0; ni < 2; ++ni) {
      const float rl = 1.f / (lt[ni] + lred[qg * 32 + ni * 16 + l15]);
      const int qs = q0 + ni * 16 + l15;
#pragma unroll
      for (int di = 0; di < 4; ++di) {
        float v0 = (o_acc[di][ni][0] + red[qg * 2112 + (di * 16 + quad * 4 + 0) * 33 + ni * 16 + l15]) * rl;
        float v1 = (o_acc[di][ni][1] + red[qg * 2112 + (di * 16 + quad * 4 + 1) * 33 + ni * 16 + l15]) * rl;
        float v2 = (o_acc[di][ni][2] + red[qg * 2112 + (di * 16 + quad * 4 + 2) * 33 + ni * 16 + l15]) * rl;
        float v3 = (o_acc[di][ni][3] + red[qg * 2112 + (di * 16 + quad * 4 + 3) * 33 + ni * 16 + l15]) * rl;
        uint2 ov;
        ov.x = pkbf(v0, v1);
        ov.y = pkbf(v2, v3);
        *(uint2*)(Ctx + (size_t)(b * SEQ + qs) * EDIM + h * 64 + di * 16 + quad * 4) = ov;
      }
    }
  }
#undef STAGE_KV
}

// ---------------- launch ----------------
extern "C" void kernel_launch(void* const* d_in, const int* in_sizes, int n_in,
                              void* d_out, int out_size, void* d_ws, size_t ws_size,
                              hipStream_t stream) {
  const float* x  = (const float*)d_in[0];
  const float* Wq = (const float*)d_in[1];
  const float* Wk = (const float*)d_in[2];
  const float* Wv = (const float*)d_in[3];
  const float* Wo = (const float*)d_in[4];
  float* out = (float*)d_out;
  u16* ws = (u16*)d_ws;

  const size_t ME = (size_t)BATCH * SEQ * EDIM;  // 8388608
  u16* Xb   = ws;                                // [8192][1024] bf16
  u16* Wqkv = Xb + ME;                           // [3072][1024]
  u16* Wob  = Wqkv + 3u * 1024 * 1024;           // [1024][1024]
  u16* Qb   = Wob + 1024u * 1024;                // [B,S,E] (pre-scaled)
  u16* Kb   = Qb + ME;
  u16* Vpb  = Kb + ME;                           // V^T permuted: [b*1024+hd][2048]
  u16* Ctx  = Vpb + ME;                          // ends at ~88 MB

  const float qscale = 0.125f * 1.44269504f;     // 1/sqrt(64) * log2(e)

  cvt_all<<<dim3(512, 5), 256, 0, stream>>>(x, Wq, Wk, Wv, Wo, Xb, Wqkv, Wob, qscale);
  gemm_tn<0><<<dim3(64, 16), 256, 0, stream>>>(Wqkv, Xb, (void*)Qb, Kb, nullptr, EDIM);
  gemm_tn<2><<<dim3(64, 8), 256, 0, stream>>>(Wqkv + 2u * 1048576, Xb, nullptr, nullptr, Vpb, EDIM);
  attn_fwd<<<dim3(64, 16), 512, 0, stream>>>(Qb, Kb, Vpb, Ctx);
  gemm_tn<1><<<dim3(64, 8), 256, 0, stream>>>(Wob, Ctx, (void*)out, nullptr, nullptr, EDIM);
}